// Round 7
// baseline (96.362 us; speedup 1.0000x reference)
//
#include <hip/hip_runtime.h>
#include <cstdint>
#include <cstddef>

typedef _Float16 f16;
typedef f16 f16x8 __attribute__((ext_vector_type(8)));
typedef f16 f16x4 __attribute__((ext_vector_type(4)));
typedef float f32x4 __attribute__((ext_vector_type(4)));

typedef const __attribute__((address_space(1))) void gvoid;
typedef __attribute__((address_space(3))) void lvoid;

constexpr int NS = 2048;     // sites
constexpr int NB = 65536;    // bonds
// d_in order: sites, bonds, states, indices1, W1, b1, W2, b2, W3, b3 (all f32, idx int32)

// ---------------- pack (blocks 0..63) + count (blocks 64..319) ----------------
__global__ void pack_count_kernel(const float* __restrict__ W1, const float* __restrict__ W2,
                                  const float* __restrict__ W3, f16* __restrict__ pw1,
                                  f16* __restrict__ pw2, f16* __restrict__ pw3,
                                  const int* __restrict__ idx, int* __restrict__ counts) {
    if (blockIdx.x < 64) {
        int t = blockIdx.x * 256 + threadIdx.x;   // 16384 threads
        int tt = t >> 6, l = t & 63;
        const float* W; f16* dst; int N, tloc, kt, nt;
        if (tt < 96)       { W = W1; dst = pw1; N = 256; tloc = tt;       kt = tloc >> 4; nt = tloc & 15; }
        else if (tt < 224) { W = W2; dst = pw2; N = 256; tloc = tt - 96;  kt = tloc >> 4; nt = tloc & 15; }
        else               { W = W3; dst = pw3; N = 64;  tloc = tt - 224; kt = tloc >> 2; nt = tloc & 3;  }
        int kbase = kt * 32 + (l >> 4) * 8;
        int n = nt * 16 + (l & 15);
        f16x8 o;
        #pragma unroll
        for (int j = 0; j < 8; ++j) o[j] = (f16)W[(size_t)(kbase + j) * N + n];
        *reinterpret_cast<f16x8*>(&dst[(size_t)(tloc * 64 + l) * 8]) = o;
    } else {
        int i = (blockIdx.x - 64) * 256 + threadIdx.x;   // 65536 threads
        atomicAdd(&counts[idx[i]], 1);
    }
}

__global__ void scan_kernel(const int* __restrict__ counts, int* __restrict__ offsets) {
    int l = threadIdx.x;            // 64 lanes, each owns 32 contiguous sites
    int c[32]; int run = 0;
    #pragma unroll
    for (int i = 0; i < 32; ++i) { c[i] = run; run += counts[l * 32 + i]; }
    int incl = run;
    #pragma unroll
    for (int d = 1; d < 64; d <<= 1) { int v = __shfl_up(incl, d); if (l >= d) incl += v; }
    int excl = incl - run;
    #pragma unroll
    for (int i = 0; i < 32; ++i) offsets[l * 32 + i] = excl + c[i];
}

__global__ void fill_kernel(const int* __restrict__ idx, const int* __restrict__ offsets,
                            int* __restrict__ cursor, int* __restrict__ bucket) {
    int i = blockIdx.x * 256 + threadIdx.x;   // grid exactly 65536
    int s = idx[i];
    int pos = atomicAdd(&cursor[s], 1);
    bucket[offsets[s] + pos] = i;
}

// ---------------- fused gather-pool (global_load_lds ring) + 3-layer MLP ----------------
// block = (batch b, 32-site chunk). 256 threads, 4 waves. Wave w owns sites w*8..w*8+7,
// processed one at a time through an 8-slot LDS ring (slot = 1KB = 4 bond rows):
//   prologue: 8 global_load_lds (per-lane addr: row id[4j+g], chunk c; lane g=l>>4, c=l&15)
//   steady:   vmcnt(7) -> ds_read slot k -> lgkmcnt(0) -> reissue slot k+8 (same ring pos) -> pred-add
// Loads never drain to 0 in the main loop (T3/T4 counted-vmcnt).
__global__ __launch_bounds__(256) void fused_kernel(
    const float* __restrict__ bonds, const float* __restrict__ sites, const float* __restrict__ states,
    const int* __restrict__ counts, const int* __restrict__ offsets, const int* __restrict__ bucket,
    const float* __restrict__ b1, const float* __restrict__ b2, const float* __restrict__ b3,
    const f16x8* __restrict__ pw1, const f16x8* __restrict__ pw2, const f16x8* __restrict__ pw3,
    float* __restrict__ out) {
    constexpr int STR = 280;                 // f16 row stride: 560B rows, 16B-aligned
    __shared__ f16 bufA[32 * STR];           // V (192 cols), later h2 (256 cols)   17920 B
    __shared__ f16 bufB[32 * STR];           // id queue (32x128 ints), then h1     17920 B
    __shared__ float stg[4 * 8 * 256];       // 4 waves x 8-slot ring x 1KB         32768 B
    int t = threadIdx.x;
    int w = t >> 6, lane = t & 63;
    int arow = lane & 15, ag = lane >> 4;
    int blk = blockIdx.x;
    int b = blk >> 6;                        // 64 chunks per batch
    int s0 = (blk & 63) * 32;                // first site of chunk
    int m0 = b * NS + s0;                    // first output row

    int* qlds = reinterpret_cast<int*>(bufB);    // [32][128] ids = 16384 B <= 17920

    // per-wave preload of the 8 site counts (lane&7 -> site w*8+(lane&7))
    int cnt_r = counts[s0 + w * 8 + (lane & 7)];

    // ---- stage id queue (coalesced per 16-lane group) ----
    {
        #pragma unroll
        for (int sg = 0; sg < 2; ++sg) {
            int srow = sg * 16 + (t >> 4);
            int cnt = counts[s0 + srow]; if (cnt > 128) cnt = 128;
            int soff = offsets[s0 + srow];
            for (int j = t & 15; j < cnt; j += 16) qlds[srow * 128 + j] = bucket[soff + j];
        }
    }
    // ---- stage sites (cols 64..127) and states (cols 128..191) ----
    {
        #pragma unroll
        for (int p = 0; p < 2; ++p) {
            int i = p * 256 + t;             // 512: 32 rows x 16 chunks
            int row = i >> 4, c4 = i & 15;
            f32x4 v = *reinterpret_cast<const f32x4*>(sites + (size_t)(m0 + row) * 64 + c4 * 4);
            f16x4 h = { (f16)v[0], (f16)v[1], (f16)v[2], (f16)v[3] };
            *reinterpret_cast<f16x4*>(&bufA[row * STR + 64 + c4 * 4]) = h;
        }
        f32x4 v = *reinterpret_cast<const f32x4*>(states + (size_t)b * 64 + (t & 15) * 4);
        f16x4 h = { (f16)v[0], (f16)v[1], (f16)v[2], (f16)v[3] };
        #pragma unroll
        for (int p = 0; p < 2; ++p) {
            int row = p * 16 + (t >> 4), c4 = t & 15;
            *reinterpret_cast<f16x4*>(&bufA[row * STR + 128 + c4 * 4]) = h;
        }
    }
    __syncthreads();   // drains vmcnt/lgkm: clean counter slate for the ring

    // ---- gather-mean via global_load_lds ring (cols 0..63) ----
    {
        const float* bbase = bonds + (size_t)b * NB * 64;
        float* stgw = stg + w * 2048;        // this wave's 8 x 256-float ring
        int g = lane >> 4, c = lane & 15;
        for (int si = 0; si < 8; ++si) {
            int lrow = w * 8 + si;
            int cnt = __shfl(cnt_r, si);
            int cmax = cnt < 128 ? cnt : 128;
            const int* q = qlds + lrow * 128;
            f32x4 acc = {0.f, 0.f, 0.f, 0.f};
            if (cmax > 0) {
                int n = (cmax + 3) >> 2;     // slots (4 rows each)
                if (n >= 8) {
                    #pragma unroll
                    for (int j = 0; j < 8; ++j) {   // prologue: fill ring
                        int qi = 4 * j + g; qi = qi < cmax ? qi : cmax - 1;
                        int id = q[qi];
                        const float* gp = bbase + (size_t)id * 64 + c * 4;
                        __builtin_amdgcn_global_load_lds((gvoid*)gp, (lvoid*)(stgw + j * 256), 16, 0, 0);
                    }
                    for (int k = 0; k < n; ++k) {
                        asm volatile("s_waitcnt vmcnt(7)" ::: "memory");
                        __builtin_amdgcn_sched_barrier(0);
                        f32x4 v = *reinterpret_cast<const f32x4*>(stgw + (k & 7) * 256 + lane * 4);
                        int kp = k + 8;
                        if (kp < n) {
                            int qi = 4 * kp + g; qi = qi < cmax ? qi : cmax - 1;
                            int id = q[qi];
                            asm volatile("s_waitcnt lgkmcnt(0)" ::: "memory");  // v + id in regs
                            __builtin_amdgcn_sched_barrier(0);
                            const float* gp = bbase + (size_t)id * 64 + c * 4;
                            __builtin_amdgcn_global_load_lds((gvoid*)gp, (lvoid*)(stgw + (k & 7) * 256), 16, 0, 0);
                        }
                        if (4 * k + g < cmax) acc += v;
                    }
                    // ring exits drained: last slot issued == last slot consumed
                } else {
                    for (int j = 0; j < n; ++j) {
                        int qi = 4 * j + g; qi = qi < cmax ? qi : cmax - 1;
                        int id = q[qi];
                        const float* gp = bbase + (size_t)id * 64 + c * 4;
                        __builtin_amdgcn_global_load_lds((gvoid*)gp, (lvoid*)(stgw + j * 256), 16, 0, 0);
                    }
                    asm volatile("s_waitcnt vmcnt(0)" ::: "memory");
                    __builtin_amdgcn_sched_barrier(0);
                    for (int k = 0; k < n; ++k) {
                        f32x4 v = *reinterpret_cast<const f32x4*>(stgw + k * 256 + lane * 4);
                        if (4 * k + g < cmax) acc += v;
                    }
                }
            }
            #pragma unroll
            for (int e = 0; e < 4; ++e) {    // reduce the 4 row-groups
                acc[e] += __shfl_xor(acc[e], 16);
                acc[e] += __shfl_xor(acc[e], 32);
            }
            float inv = 1.0f / (float)(cnt > 1 ? cnt : 1);
            acc *= inv;
            if (g == 0) {
                f16x4 h = { (f16)acc[0], (f16)acc[1], (f16)acc[2], (f16)acc[3] };
                *reinterpret_cast<f16x4*>(&bufA[lrow * STR + c * 4]) = h;
            }
        }
    }
    __syncthreads();   // V complete; queue dead -> bufB becomes h1

    // ---- GEMM1: h1 = relu(V @ W1 + b1), K=192 ----
    {
        f32x4 acc[2][4];
        #pragma unroll
        for (int ni = 0; ni < 4; ++ni) {
            float bv = b1[w * 64 + ni * 16 + arow];
            acc[0][ni] = f32x4{bv, bv, bv, bv};
            acc[1][ni] = f32x4{bv, bv, bv, bv};
        }
        #pragma unroll
        for (int kt = 0; kt < 6; ++kt) {
            f16x8 af[2], bfr[4];
            #pragma unroll
            for (int mi = 0; mi < 2; ++mi)
                af[mi] = *reinterpret_cast<const f16x8*>(&bufA[(mi * 16 + arow) * STR + kt * 32 + ag * 8]);
            #pragma unroll
            for (int ni = 0; ni < 4; ++ni) bfr[ni] = pw1[(kt * 16 + w * 4 + ni) * 64 + lane];
            #pragma unroll
            for (int mi = 0; mi < 2; ++mi)
                #pragma unroll
                for (int ni = 0; ni < 4; ++ni)
                    acc[mi][ni] = __builtin_amdgcn_mfma_f32_16x16x32_f16(af[mi], bfr[ni], acc[mi][ni], 0, 0, 0);
        }
        #pragma unroll
        for (int mi = 0; mi < 2; ++mi)
            #pragma unroll
            for (int ni = 0; ni < 4; ++ni)
                #pragma unroll
                for (int j = 0; j < 4; ++j) {
                    float x = acc[mi][ni][j]; x = x > 0.f ? x : 0.f;
                    bufB[(mi * 16 + ag * 4 + j) * STR + w * 64 + ni * 16 + arow] = (f16)x;
                }
    }
    __syncthreads();

    // ---- GEMM2: h2 = relu(h1 @ W2 + b2), K=256 ----
    {
        f32x4 acc[2][4];
        #pragma unroll
        for (int ni = 0; ni < 4; ++ni) {
            float bv = b2[w * 64 + ni * 16 + arow];
            acc[0][ni] = f32x4{bv, bv, bv, bv};
            acc[1][ni] = f32x4{bv, bv, bv, bv};
        }
        #pragma unroll
        for (int kt = 0; kt < 8; ++kt) {
            f16x8 af[2], bfr[4];
            #pragma unroll
            for (int mi = 0; mi < 2; ++mi)
                af[mi] = *reinterpret_cast<const f16x8*>(&bufB[(mi * 16 + arow) * STR + kt * 32 + ag * 8]);
            #pragma unroll
            for (int ni = 0; ni < 4; ++ni) bfr[ni] = pw2[(kt * 16 + w * 4 + ni) * 64 + lane];
            #pragma unroll
            for (int mi = 0; mi < 2; ++mi)
                #pragma unroll
                for (int ni = 0; ni < 4; ++ni)
                    acc[mi][ni] = __builtin_amdgcn_mfma_f32_16x16x32_f16(af[mi], bfr[ni], acc[mi][ni], 0, 0, 0);
        }
        __syncthreads();   // all h1 reads done before overwriting bufA
        #pragma unroll
        for (int mi = 0; mi < 2; ++mi)
            #pragma unroll
            for (int ni = 0; ni < 4; ++ni)
                #pragma unroll
                for (int j = 0; j < 4; ++j) {
                    float x = acc[mi][ni][j]; x = x > 0.f ? x : 0.f;
                    bufA[(mi * 16 + ag * 4 + j) * STR + w * 64 + ni * 16 + arow] = (f16)x;
                }
    }
    __syncthreads();

    // ---- GEMM3: out = relu(h2 @ W3 + b3), K=256, N=64 ----
    {
        f32x4 acc[2];
        float bv = b3[w * 16 + arow];
        acc[0] = f32x4{bv, bv, bv, bv};
        acc[1] = f32x4{bv, bv, bv, bv};
        #pragma unroll
        for (int kt = 0; kt < 8; ++kt) {
            f16x8 bfr = pw3[(kt * 4 + w) * 64 + lane];
            #pragma unroll
            for (int mi = 0; mi < 2; ++mi) {
                f16x8 af = *reinterpret_cast<const f16x8*>(&bufA[(mi * 16 + arow) * STR + kt * 32 + ag * 8]);
                acc[mi] = __builtin_amdgcn_mfma_f32_16x16x32_f16(af, bfr, acc[mi], 0, 0, 0);
            }
        }
        #pragma unroll
        for (int mi = 0; mi < 2; ++mi)
            #pragma unroll
            for (int j = 0; j < 4; ++j) {
                float x = acc[mi][j]; x = x > 0.f ? x : 0.f;
                out[(size_t)(m0 + mi * 16 + ag * 4 + j) * 64 + w * 16 + arow] = x;
            }
    }
}

extern "C" void kernel_launch(void* const* d_in, const int* in_sizes, int n_in,
                              void* d_out, int out_size, void* d_ws, size_t ws_size,
                              hipStream_t stream) {
    (void)in_sizes; (void)n_in; (void)out_size; (void)ws_size;
    const float* sites  = (const float*)d_in[0];
    const float* bonds  = (const float*)d_in[1];
    const float* states = (const float*)d_in[2];
    const int*   idx    = (const int*)d_in[3];
    const float* W1 = (const float*)d_in[4];
    const float* b1 = (const float*)d_in[5];
    const float* W2 = (const float*)d_in[6];
    const float* b2 = (const float*)d_in[7];
    const float* W3 = (const float*)d_in[8];
    const float* b3 = (const float*)d_in[9];
    float* out = (float*)d_out;

    char* ws = (char*)d_ws;
    f16* pw1     = (f16*)ws;                      // 96*512 f16
    f16* pw2     = pw1 + 96 * 512;                // 128*512 f16
    f16* pw3     = pw2 + 128 * 512;               // 32*512 f16  (total 262144 B)
    int* counts  = (int*)(ws + 262144);           // 2048 * 4
    int* cursor  = (int*)(ws + 262144 + 8192);    // 2048 * 4
    int* offsets = (int*)(ws + 262144 + 16384);   // 2048 * 4
    int* bucket  = (int*)(ws + 262144 + 24576);   // 65536 * 4

    hipMemsetAsync(counts, 0, 16384, stream);     // zeros counts + cursor
    pack_count_kernel<<<320, 256, 0, stream>>>(W1, W2, W3, pw1, pw2, pw3, idx, counts);
    scan_kernel<<<1, 64, 0, stream>>>(counts, offsets);
    fill_kernel<<<256, 256, 0, stream>>>(idx, offsets, cursor, bucket);
    fused_kernel<<<1024, 256, 0, stream>>>(bonds, sites, states, counts, offsets, bucket,
                                           b1, b2, b3,
                                           (const f16x8*)pw1, (const f16x8*)pw2, (const f16x8*)pw3, out);
}